// Round 1
// baseline (388.971 us; speedup 1.0000x reference)
//
#include <hip/hip_runtime.h>
#include <stdint.h>

typedef unsigned short u16;
typedef __bf16 bf16x8 __attribute__((ext_vector_type(8)));
typedef float f32x4 __attribute__((ext_vector_type(4)));

#define B_ 2
#define T_ 2048
#define H_ 16

// ---------- bf16 helpers (RNE) ----------
__device__ __forceinline__ u16 f2b(float f) {
  unsigned u = __float_as_uint(f);
  u += 0x7fffu + ((u >> 16) & 1u);
  return (u16)(u >> 16);
}
__device__ __forceinline__ float b2f(u16 v) {
  return __uint_as_float(((unsigned)v) << 16);
}

// ---------- convert x fp32 -> bf16 ----------
__global__ __launch_bounds__(256) void conv_x_kernel(const float* __restrict__ in,
                                                     u16* __restrict__ out) {
  int i = (blockIdx.x * 256 + threadIdx.x) * 4;
  float4 v = *reinterpret_cast<const float4*>(in + i);
  union { u16 h[4]; unsigned long long ll; } pk;
  pk.h[0] = f2b(v.x); pk.h[1] = f2b(v.y); pk.h[2] = f2b(v.z); pk.h[3] = f2b(v.w);
  *reinterpret_cast<unsigned long long*>(out + i) = pk.ll;
}

// ---------- transpose weight fp32 [K][N] -> bf16 Wt[row_off+n][k] ----------
__global__ __launch_bounds__(256) void transpose_w_kernel(const float* __restrict__ W,
                                                          int K, int N,
                                                          u16* __restrict__ Wt,
                                                          int ldt, int row_off) {
  __shared__ float tile[32][33];
  int n0 = blockIdx.x * 32, k0 = blockIdx.y * 32;
  int cx = threadIdx.x, ry = threadIdx.y;
  #pragma unroll
  for (int i = 0; i < 4; i++)
    tile[ry + i * 8][cx] = W[(size_t)(k0 + ry + i * 8) * N + n0 + cx];
  __syncthreads();
  #pragma unroll
  for (int i = 0; i < 4; i++)
    Wt[(size_t)(row_off + n0 + ry + i * 8) * ldt + k0 + cx] = f2b(tile[cx][ry + i * 8]);
}

// ---------- GEMM: C[M][N] = A[M][K] (bf16) * Bt[N][K]^T (bf16) ----------
// grid: (N/128, M/128), block 256 (4 waves), each wave 64x64 via 4x4 MFMA frags
__global__ __launch_bounds__(256) void gemm_bt(const u16* __restrict__ A, int lda,
                                               const u16* __restrict__ Bt, int ldb,
                                               void* __restrict__ Cout, int ldc,
                                               int K, int f32out) {
  __shared__ u16 As[128][40];  // pad 40: 2-way bank conflict only
  __shared__ u16 Bs[128][40];
  const int tid = threadIdx.x;
  const int wave = tid >> 6, lane = tid & 63;
  const int wr = wave >> 1, wc = wave & 1;
  const int l15 = lane & 15, l4 = lane >> 4;
  const int m0 = blockIdx.y * 128, n0 = blockIdx.x * 128;
  const int r_st = tid >> 2, c_st = (tid & 3) * 8;

  f32x4 acc[4][4];
  const f32x4 fzero = {0.f, 0.f, 0.f, 0.f};
  #pragma unroll
  for (int m = 0; m < 4; m++)
    #pragma unroll
    for (int n = 0; n < 4; n++)
      acc[m][n] = fzero;

  const u16* Aabase = A + (size_t)(m0 + r_st) * lda + c_st;
  const u16* Bbase  = Bt + (size_t)(n0 + r_st) * ldb + c_st;

  for (int k0 = 0; k0 < K; k0 += 32) {
    __syncthreads();
    int4 a0 = *reinterpret_cast<const int4*>(Aabase + k0);
    int4 a1 = *reinterpret_cast<const int4*>(Aabase + (size_t)64 * lda + k0);
    int4 b0 = *reinterpret_cast<const int4*>(Bbase + k0);
    int4 b1 = *reinterpret_cast<const int4*>(Bbase + (size_t)64 * ldb + k0);
    *reinterpret_cast<int4*>(&As[r_st][c_st]) = a0;
    *reinterpret_cast<int4*>(&As[r_st + 64][c_st]) = a1;
    *reinterpret_cast<int4*>(&Bs[r_st][c_st]) = b0;
    *reinterpret_cast<int4*>(&Bs[r_st + 64][c_st]) = b1;
    __syncthreads();
    bf16x8 af[4], bfr[4];
    #pragma unroll
    for (int m = 0; m < 4; m++)
      af[m] = *reinterpret_cast<const bf16x8*>(&As[wr * 64 + m * 16 + l15][l4 * 8]);
    #pragma unroll
    for (int n = 0; n < 4; n++)
      bfr[n] = *reinterpret_cast<const bf16x8*>(&Bs[wc * 64 + n * 16 + l15][l4 * 8]);
    #pragma unroll
    for (int m = 0; m < 4; m++)
      #pragma unroll
      for (int n = 0; n < 4; n++)
        acc[m][n] = __builtin_amdgcn_mfma_f32_16x16x32_bf16(af[m], bfr[n], acc[m][n], 0, 0, 0);
  }

  const int row_base = m0 + wr * 64 + l4 * 4;
  const int col_base = n0 + wc * 64 + l15;
  if (f32out) {
    float* Cf = (float*)Cout;
    #pragma unroll
    for (int m = 0; m < 4; m++)
      #pragma unroll
      for (int n = 0; n < 4; n++)
        #pragma unroll
        for (int r = 0; r < 4; r++)
          Cf[(size_t)(row_base + m * 16 + r) * ldc + col_base + n * 16] = acc[m][n][r];
  } else {
    u16* Cb = (u16*)Cout;
    #pragma unroll
    for (int m = 0; m < 4; m++)
      #pragma unroll
      for (int n = 0; n < 4; n++)
        #pragma unroll
        for (int r = 0; r < 4; r++)
          Cb[(size_t)(row_base + m * 16 + r) * ldc + col_base + n * 16] = f2b(acc[m][n][r]);
  }
}

// ---------- rope (in place on cols [1024,2048) of a [4096][2048] bf16 buffer) ----------
__global__ __launch_bounds__(256) void rope_kernel(u16* __restrict__ buf,
                                                   const float* __restrict__ cosT,
                                                   const float* __restrict__ sinT) {
  int idx = blockIdx.x * 256 + threadIdx.x;   // 4096 rows * 16 heads * 32 pairs
  int i  = idx & 31;
  int hh = (idx >> 5) & 15;
  int r  = idx >> 9;
  int t  = r & (T_ - 1);
  size_t base = (size_t)r * 2048 + 1024 + hh * 64;
  float x1 = b2f(buf[base + i]);
  float x2 = b2f(buf[base + i + 32]);
  float c1 = cosT[t * 64 + i],      s1 = sinT[t * 64 + i];
  float c2 = cosT[t * 64 + i + 32], s2 = sinT[t * 64 + i + 32];
  buf[base + i]      = f2b(x1 * c1 - x2 * s1);
  buf[base + i + 32] = f2b(x2 * c2 + x1 * s2);
}

// ---------- causal flash attention ----------
// grid (T/64, B*H), 256 thr (4 waves); wave w owns q rows [q0+16w, q0+16w+16)
__global__ __launch_bounds__(256) void attn_kernel(const u16* __restrict__ qo,
                                                   const u16* __restrict__ kvo,
                                                   u16* __restrict__ yb) {
  __shared__ u16 K_lds[64][136];    // [kv][feat 0..127], pad 136
  __shared__ u16 V_lds[64][72];     // transposed: [d][kv]
  __shared__ u16 P_lds[4][16][72];  // per-wave P strip
  const int tid = threadIdx.x;
  const int wave = tid >> 6, lane = tid & 63;
  const int l15 = lane & 15, l4 = lane >> 4;
  const int b = blockIdx.y >> 4, h = blockIdx.y & 15;
  const int q0 = blockIdx.x * 64;

  bf16x8 qf[4];
  {
    const size_t row = (size_t)(b * T_ + q0 + wave * 16 + l15);
    const u16* qb = qo + row * 2048 + h * 64;
    qf[0] = *reinterpret_cast<const bf16x8*>(qb + l4 * 8);
    qf[1] = *reinterpret_cast<const bf16x8*>(qb + 32 + l4 * 8);
    qf[2] = *reinterpret_cast<const bf16x8*>(qb + 1024 + l4 * 8);
    qf[3] = *reinterpret_cast<const bf16x8*>(qb + 1024 + 32 + l4 * 8);
  }

  const f32x4 fzero = {0.f, 0.f, 0.f, 0.f};
  f32x4 o_acc[4];
  #pragma unroll
  for (int c = 0; c < 4; c++) o_acc[c] = fzero;
  float m_run[4] = {-1e30f, -1e30f, -1e30f, -1e30f};
  float l_run[4] = {0.f, 0.f, 0.f, 0.f};

  for (int kv0 = 0; kv0 < q0 + 64; kv0 += 64) {
    __syncthreads();
    // stage K tile: 64 rows x 128 feats (content | rope)
    #pragma unroll
    for (int i = 0; i < 4; i++) {
      int chunk = tid + 256 * i;
      int r = chunk >> 4;
      int fc = (chunk & 15) * 8;
      const u16* src = kvo + (size_t)(b * T_ + kv0 + r) * 2048 + h * 64
                           + (fc < 64 ? fc : 960 + fc);
      *reinterpret_cast<int4*>(&K_lds[r][fc]) = *reinterpret_cast<const int4*>(src);
    }
    // stage V tile transposed: V_lds[d][kv]
    #pragma unroll
    for (int i = 0; i < 2; i++) {
      int idx = tid + 256 * i;
      int r = idx >> 3, dc = (idx & 7) * 8;
      const u16* src = kvo + (size_t)(b * T_ + kv0 + r) * 2048 + h * 64 + dc;
      int4 v = *reinterpret_cast<const int4*>(src);
      const u16* vs = reinterpret_cast<const u16*>(&v);
      #pragma unroll
      for (int j = 0; j < 8; j++) V_lds[dc + j][r] = vs[j];
    }
    __syncthreads();

    // QK^T: S strip 16x64 per wave
    f32x4 s_acc[4];
    #pragma unroll
    for (int c = 0; c < 4; c++) s_acc[c] = fzero;
    #pragma unroll
    for (int c = 0; c < 4; c++)
      #pragma unroll
      for (int s = 0; s < 4; s++) {
        bf16x8 kf = *reinterpret_cast<const bf16x8*>(&K_lds[c * 16 + l15][s * 32 + l4 * 8]);
        s_acc[c] = __builtin_amdgcn_mfma_f32_16x16x32_bf16(qf[s], kf, s_acc[c], 0, 0, 0);
      }

    const bool diag = (kv0 == q0);
    float p[4][4];
    #pragma unroll
    for (int r = 0; r < 4; r++) {
      float mx = -1e30f;
      #pragma unroll
      for (int c = 0; c < 4; c++) {
        float s = s_acc[c][r] * 0.125f;
        if (diag) {
          int qi = wave * 16 + l4 * 4 + r;
          int ki = c * 16 + l15;
          if (ki > qi) s = -1e30f;
        }
        p[c][r] = s;
        mx = fmaxf(mx, s);
      }
      mx = fmaxf(mx, __shfl_xor(mx, 1));
      mx = fmaxf(mx, __shfl_xor(mx, 2));
      mx = fmaxf(mx, __shfl_xor(mx, 4));
      mx = fmaxf(mx, __shfl_xor(mx, 8));
      float m_new = fmaxf(m_run[r], mx);
      float corr = __expf(m_run[r] - m_new);
      float rsum = 0.f;
      #pragma unroll
      for (int c = 0; c < 4; c++) {
        float pe = __expf(p[c][r] - m_new);
        p[c][r] = pe;
        rsum += pe;
      }
      rsum += __shfl_xor(rsum, 1);
      rsum += __shfl_xor(rsum, 2);
      rsum += __shfl_xor(rsum, 4);
      rsum += __shfl_xor(rsum, 8);
      l_run[r] = l_run[r] * corr + rsum;
      m_run[r] = m_new;
      #pragma unroll
      for (int c = 0; c < 4; c++) o_acc[c][r] *= corr;
    }

    // repack P (D-layout) -> A-layout via per-wave LDS
    #pragma unroll
    for (int c = 0; c < 4; c++)
      #pragma unroll
      for (int r = 0; r < 4; r++)
        P_lds[wave][l4 * 4 + r][c * 16 + l15] = f2b(p[c][r]);

    bf16x8 pf0 = *reinterpret_cast<const bf16x8*>(&P_lds[wave][l15][l4 * 8]);
    bf16x8 pf1 = *reinterpret_cast<const bf16x8*>(&P_lds[wave][l15][32 + l4 * 8]);
    #pragma unroll
    for (int c = 0; c < 4; c++) {
      bf16x8 v0 = *reinterpret_cast<const bf16x8*>(&V_lds[c * 16 + l15][l4 * 8]);
      bf16x8 v1 = *reinterpret_cast<const bf16x8*>(&V_lds[c * 16 + l15][32 + l4 * 8]);
      o_acc[c] = __builtin_amdgcn_mfma_f32_16x16x32_bf16(pf0, v0, o_acc[c], 0, 0, 0);
      o_acc[c] = __builtin_amdgcn_mfma_f32_16x16x32_bf16(pf1, v1, o_acc[c], 0, 0, 0);
    }
  }

  #pragma unroll
  for (int c = 0; c < 4; c++)
    #pragma unroll
    for (int r = 0; r < 4; r++) {
      int q = q0 + wave * 16 + l4 * 4 + r;
      float ov = o_acc[c][r] / l_run[r];
      yb[(size_t)(b * T_ + q) * 1024 + h * 64 + c * 16 + l15] = f2b(ov);
    }
}

// ---------- launcher ----------
extern "C" void kernel_launch(void* const* d_in, const int* in_sizes, int n_in,
                              void* d_out, int out_size, void* d_ws, size_t ws_size,
                              hipStream_t stream) {
  const float* x         = (const float*)d_in[0];
  const float* cosT      = (const float*)d_in[1];
  const float* sinT      = (const float*)d_in[2];
  const float* W_kv_down = (const float*)d_in[3];
  const float* W_kv_up   = (const float*)d_in[4];
  const float* W_k_rope  = (const float*)d_in[5];
  const float* W_q_down  = (const float*)d_in[6];
  const float* W_q_up    = (const float*)d_in[7];
  const float* W_q_rope  = (const float*)d_in[8];
  const float* W_out     = (const float*)d_in[9];
  float* out = (float*)d_out;
  char* ws = (char*)d_ws;

  // ws layout (bytes), total ~53.2 MB
  u16* xb    = (u16*)(ws + 0);              // 4096x1024 bf16 (8 MB); reused as yb later
  u16* lat   = (u16*)(ws + 8388608);        // 4096x640
  u16* WdT   = (u16*)(ws + 13631488);       // 640x1024
  u16* WkvT  = (u16*)(ws + 14942208);       // 2048x256
  u16* WqT   = (u16*)(ws + 15990784);       // 2048x384
  u16* WoutT = (u16*)(ws + 17563648);       // 1024x1024
  u16* kvo   = (u16*)(ws + 19660800);       // 4096x2048 (kv_up | k_rope)
  u16* qo    = (u16*)(ws + 36438016);       // 4096x2048 (q_content | q_rope)
  u16* yb    = (u16*)(ws + 0);              // 4096x1024 (reuse xb region)

  dim3 tb(32, 8);
  conv_x_kernel<<<4096, 256, 0, stream>>>(x, xb);
  transpose_w_kernel<<<dim3(8, 32),  tb, 0, stream>>>(W_kv_down, 1024, 256,  WdT,  1024, 0);
  transpose_w_kernel<<<dim3(12, 32), tb, 0, stream>>>(W_q_down,  1024, 384,  WdT,  1024, 256);
  transpose_w_kernel<<<dim3(32, 8),  tb, 0, stream>>>(W_kv_up,   256,  1024, WkvT, 256,  0);
  transpose_w_kernel<<<dim3(32, 8),  tb, 0, stream>>>(W_k_rope,  256,  1024, WkvT, 256,  1024);
  transpose_w_kernel<<<dim3(32, 12), tb, 0, stream>>>(W_q_up,    384,  1024, WqT,  384,  0);
  transpose_w_kernel<<<dim3(32, 12), tb, 0, stream>>>(W_q_rope,  384,  1024, WqT,  384,  1024);
  transpose_w_kernel<<<dim3(32, 32), tb, 0, stream>>>(W_out,     1024, 1024, WoutT, 1024, 0);

  // lat = xb @ [W_kv_down | W_q_down]   (M=4096, K=1024, N=640)
  gemm_bt<<<dim3(5, 32), 256, 0, stream>>>(xb, 1024, WdT, 1024, lat, 640, 1024, 0);
  // kvo = lat[:, :256] @ [W_kv_up | W_k_rope]  (K=256, N=2048)
  gemm_bt<<<dim3(16, 32), 256, 0, stream>>>(lat, 640, WkvT, 256, kvo, 2048, 256, 0);
  // qo  = lat[:, 256:] @ [W_q_up | W_q_rope]   (K=384, N=2048)
  gemm_bt<<<dim3(16, 32), 256, 0, stream>>>(lat + 256, 640, WqT, 384, qo, 2048, 384, 0);

  rope_kernel<<<8192, 256, 0, stream>>>(kvo, cosT, sinT);
  rope_kernel<<<8192, 256, 0, stream>>>(qo, cosT, sinT);

  attn_kernel<<<dim3(32, 32), 256, 0, stream>>>(qo, kvo, yb);

  // out = yb @ W_out (fp32 out)
  gemm_bt<<<dim3(8, 32), 256, 0, stream>>>(yb, 1024, WoutT, 1024, out, 1024, 1024, 1);
}